// Round 14
// baseline (54.027 us; speedup 1.0000x reference)
//
#include <hip/hip_runtime.h>
#include <stdint.h>

#define D_DIM 262144
#define T_DIM 24
#define S_DIM 12
#define BLK 256
#define NBLK (D_DIM / BLK)   // 1024 blocks
#define LDS_T 19             // timesteps staged in LDS (2*19*256*4 = 38.9 KB)

static constexpr float EPSF = 1e-6f;

// ---------------- threefry2x32, key = (0,0), 20 rounds ----------------
__device__ __forceinline__ void tf_round(unsigned& x0, unsigned& x1, int r) {
  x0 += x1;
  x1 = (x1 << r) | (x1 >> (32 - r));
  x1 ^= x0;
}

__device__ __forceinline__ void threefry00(unsigned c0, unsigned c1,
                                           unsigned& o0, unsigned& o1) {
  const unsigned ks0 = 0u, ks1 = 0u, ks2 = 0x1BD11BDAu;
  unsigned x0 = c0 + ks0, x1 = c1 + ks1;
  tf_round(x0, x1, 13); tf_round(x0, x1, 15); tf_round(x0, x1, 26); tf_round(x0, x1, 6);
  x0 += ks1; x1 += ks2 + 1u;
  tf_round(x0, x1, 17); tf_round(x0, x1, 29); tf_round(x0, x1, 16); tf_round(x0, x1, 24);
  x0 += ks2; x1 += ks0 + 2u;
  tf_round(x0, x1, 13); tf_round(x0, x1, 15); tf_round(x0, x1, 26); tf_round(x0, x1, 6);
  x0 += ks0; x1 += ks1 + 3u;
  tf_round(x0, x1, 17); tf_round(x0, x1, 29); tf_round(x0, x1, 16); tf_round(x0, x1, 24);
  x0 += ks1; x1 += ks2 + 4u;
  tf_round(x0, x1, 13); tf_round(x0, x1, 15); tf_round(x0, x1, 26); tf_round(x0, x1, 6);
  x0 += ks2; x1 += ks0 + 5u;
  o0 = x0; o1 = x1;
}

// bits -> uniform in [-0.99999994, 1) -> sqrt(2)*erfinv(u)  (XLA f32 path)
__device__ __forceinline__ float bits_to_normal(unsigned bits) {
  const float lo = -0.99999994f;
  const float hi = 1.0f;
  unsigned fb = (bits >> 9) | 0x3f800000u;
  float f = __uint_as_float(fb) - 1.0f;      // [0,1)
  float u = f * (hi - lo) + lo;
  u = fmaxf(lo, u);
  float w = -__logf(fmaf(-u, u, 1.0f));
  float p;
  if (w < 5.0f) {
    w = w - 2.5f;
    p = 2.81022636e-08f;
    p = fmaf(p, w, 3.43273939e-07f);
    p = fmaf(p, w, -3.5233877e-06f);
    p = fmaf(p, w, -4.39150654e-06f);
    p = fmaf(p, w, 0.00021858087f);
    p = fmaf(p, w, -0.00125372503f);
    p = fmaf(p, w, -0.00417768164f);
    p = fmaf(p, w, 0.246640727f);
    p = fmaf(p, w, 1.50140941f);
  } else {
    w = sqrtf(w) - 3.0f;
    p = -0.000200214257f;
    p = fmaf(p, w, 0.000100950558f);
    p = fmaf(p, w, 0.00134934322f);
    p = fmaf(p, w, -0.00367342844f);
    p = fmaf(p, w, 0.00573950773f);
    p = fmaf(p, w, -0.0076224613f);
    p = fmaf(p, w, 0.00943887047f);
    p = fmaf(p, w, 1.00167406f);
    p = fmaf(p, w, 2.83297682f);
  }
  return 1.41421356237309515f * (p * u);
}

// R12 (best: 42.0 us) + backward rJ/rh algebraic reconstruction (R8-proven):
//   rJ[t+1] = fJ[t+1] - l + jab^2*inv ; rh[t+1] = fh[t+1] - hb - jab*hc*inv
// (exact: same rcp value as forward cancels bitwise). Removes all 48
// backward re-reads. LDS staging kept (it pins VGPR low — R13 lesson);
// NT stores keep outputs out of the caches. Natural VGPR, no min-waves arg.
__global__ __launch_bounds__(256) void pgm_lds_kernel(
    const float* __restrict__ recog_J, const float* __restrict__ recog_h,
    const float* __restrict__ loc_p, const float* __restrict__ Tau_p,
    const float* __restrict__ Lambda_p, const float* __restrict__ A_p,
    const float* __restrict__ b_p,
    float* __restrict__ z_out,
    float* __restrict__ Ex_out, float* __restrict__ Exx_out,
    float* __restrict__ kl_partials) {
  __shared__ float s_rJ[LDS_T * BLK];
  __shared__ float s_rh[LDS_T * BLK];
  __shared__ float s_kl[BLK / 64];
  const int tid = threadIdx.x;
  const int d = blockIdx.x * BLK + tid;

#define RJ(t) (((t) < LDS_T) ? s_rJ[(t) * BLK + tid]                           \
                             : recog_J[(size_t)(t) * D_DIM + d])
#define RH(t) (((t) < LDS_T) ? s_rh[(t) * BLK + tid]                           \
                             : recog_h[(size_t)(t) * D_DIM + d])

  // ---- bulk stage: 38 direct global->LDS loads, no VGPR round-trip ----
#pragma unroll
  for (int t = 0; t < LDS_T; ++t) {
    __builtin_amdgcn_global_load_lds(
        (const __attribute__((address_space(1))) uint32_t*)(uintptr_t)(recog_J + (size_t)t * D_DIM + d),
        (__attribute__((address_space(3))) uint32_t*)(uintptr_t)(s_rJ + t * BLK + tid),
        4, 0, 0);
    __builtin_amdgcn_global_load_lds(
        (const __attribute__((address_space(1))) uint32_t*)(uintptr_t)(recog_h + (size_t)t * D_DIM + d),
        (__attribute__((address_space(3))) uint32_t*)(uintptr_t)(s_rh + t * BLK + tid),
        4, 0, 0);
  }

  // ---- params into registers; p_logZ terms (log-product form) ----
  float lam[S_DIM], Aa[S_DIM], hb[S_DIM];
  float kld = 0.0f;
  float prodA = 1.0f;   // prod_{s<11} lam_s  (sum log -> log prod)
#pragma unroll
  for (int s = 0; s < S_DIM; ++s) {
    float L = Lambda_p[s * D_DIM + d];
    float a = A_p[s * D_DIM + d];
    float bb = b_p[s * D_DIM + d];
    float l = L * L + EPSF;
    lam[s] = l;
    Aa[s] = a;
    hb[s] = l * bb;
    float wgt = (s < 11) ? 1.0f : 0.5f;   // _tile: s=0..10 twice, s=11 once
    kld += wgt * (hb[s] * bb);
    if (s < 11) prodA *= l;
  }
  float tau, tau_mu;
  {
    float Tv = Tau_p[d];
    float lv = loc_p[d];
    tau = Tv * Tv + EPSF;
    tau_mu = tau * lv;
    kld += 0.5f * (tau * lv * lv);
  }
  kld -= __logf(prodA) + 0.5f * __logf(lam[11] * tau);

  __syncthreads();   // drains vmcnt(0): staging + param loads complete

  // ---- forward information filter ----
  float fJ[T_DIM], fh[T_DIM];
  fJ[0] = tau + RJ(0);
  fh[0] = tau_mu + RH(0);
  float prodD = 1.0f;   // prod of denoms, split at t=11 to bound magnitude
#pragma unroll
  for (int t = 0; t < T_DIM - 1; ++t) {
    const int s = (t < 12) ? t : t - 12;
    float l = lam[s], a = Aa[s];
    float jab = a * l;
    float jaa = a * jab;
    float ha = -a * hb[s];
    float denom = fJ[t] + jaa;
    float inv = __builtin_amdgcn_rcpf(denom);
    float hc = fh[t] + ha;
    prodD *= denom;
    kld += -0.5f * hc * hc * inv;          // -= q_logZ step (log via product)
    if (t == 11) { kld += 0.5f * __logf(prodD); prodD = 1.0f; }
    fJ[t + 1] = l - jab * jab * inv + RJ(t + 1);
    fh[t + 1] = hb[s] + jab * hc * inv + RH(t + 1);
  }
  const float fJT = fJ[T_DIM - 1];
  const float fhT = fh[T_DIM - 1];
  const float invT = __builtin_amdgcn_rcpf(fJT);
  prodD *= fJT;
  kld += 0.5f * __logf(prodD) - 0.5f * fhT * fhT * invT;   // -= q_logZ final

  // ---- t = 23 (its KL stat term is reconstructed at backward t=22) ----
  float eps_st[S_DIM];   // stash eps[0..11] while consuming eps[12..23]
  float ExT = fhT * invT;
  float VarT = invT;
  float eps23;
  {
    unsigned o0, o1;
    threefry00((unsigned)(11 * D_DIM + d), (unsigned)(23 * D_DIM + d), o0, o1);
    eps_st[11] = bits_to_normal(o0);
    eps23 = bits_to_normal(o1);
  }
  float zT = ExT + eps23 * sqrtf(invT);
  float ExxT = VarT + ExT * ExT;
  __builtin_nontemporal_store(zT, &z_out[(T_DIM - 1) * D_DIM + d]);
  __builtin_nontemporal_store(ExT, &Ex_out[(T_DIM - 1) * D_DIM + d]);
  __builtin_nontemporal_store(ExxT, &Exx_out[(T_DIM - 1) * D_DIM + d]);

  // ---- fused backward: smoother + sampler + KL stats (no rJ/rh reads) ----
  float Exn = ExT, Varn = VarT, zn = zT, Exxp = ExxT;
#pragma unroll
  for (int t = T_DIM - 2; t >= 0; --t) {
    const int s = (t < 12) ? t : t - 12;
    float l = lam[s], a = Aa[s];
    float jab = a * l;
    float jaa = a * jab;
    float ha = -a * hb[s];
    float denom = fJ[t] + jaa;
    float inv = __builtin_amdgcn_rcpf(denom);
    float hc = fh[t] + ha;

    // KL stat terms for index t+1, reconstructed from registers
    float rJr = fJ[t + 1] - l + jab * jab * inv;
    float rhr = fh[t + 1] - hb[s] - jab * hc * inv;
    kld += -0.5f * rJr * Exxp + rhr * Exn;

    float e;
    if (t >= 12) {
      unsigned o0, o1;
      threefry00((unsigned)((t - 12) * D_DIM + d), (unsigned)(t * D_DIM + d), o0, o1);
      eps_st[t - 12] = bits_to_normal(o0);
      e = bits_to_normal(o1);
    } else {
      e = eps_st[t];
    }

    float g = jab * inv;
    float Ex = (hc + jab * Exn) * inv;
    float Var = inv + g * g * Varn;
    float zt = (hc + jab * zn) * inv + e * sqrtf(inv);
    float Exx = Var + Ex * Ex;

    __builtin_nontemporal_store(zt, &z_out[t * D_DIM + d]);
    __builtin_nontemporal_store(Ex, &Ex_out[t * D_DIM + d]);
    __builtin_nontemporal_store(Exx, &Exx_out[t * D_DIM + d]);

    Exn = Ex; Varn = Var; zn = zt; Exxp = Exx;
  }
  // KL stat terms for index 0 (rJ[0] = fJ[0]-tau, rh[0] = fh[0]-tau_mu)
  kld += -0.5f * (fJ[0] - tau) * Exxp + (fh[0] - tau_mu) * Exn;

  // ---- KL reduction: wave shuffle -> LDS -> one plain store per block ----
#pragma unroll
  for (int off = 32; off > 0; off >>= 1)
    kld += __shfl_down(kld, off, 64);
  if ((tid & 63) == 0)
    s_kl[tid >> 6] = kld;
  __syncthreads();
  if (tid == 0)
    kl_partials[blockIdx.x] = s_kl[0] + s_kl[1] + s_kl[2] + s_kl[3];
}

// Finisher: one block sums the 1024 per-block partials -> kl_out.
__global__ __launch_bounds__(256) void kl_reduce_kernel(
    const float* __restrict__ kl_partials, float* __restrict__ kl_out) {
  __shared__ float s_kl[BLK / 64];
  float v = 0.0f;
#pragma unroll
  for (int i = 0; i < NBLK / BLK; ++i)
    v += kl_partials[i * BLK + threadIdx.x];
#pragma unroll
  for (int off = 32; off > 0; off >>= 1)
    v += __shfl_down(v, off, 64);
  if ((threadIdx.x & 63) == 0)
    s_kl[threadIdx.x >> 6] = v;
  __syncthreads();
  if (threadIdx.x == 0)
    kl_out[0] = s_kl[0] + s_kl[1] + s_kl[2] + s_kl[3];
}

extern "C" void kernel_launch(void* const* d_in, const int* in_sizes, int n_in,
                              void* d_out, int out_size, void* d_ws, size_t ws_size,
                              hipStream_t stream) {
  const float* recog_J = (const float*)d_in[0];
  const float* recog_h = (const float*)d_in[1];
  const float* loc_p   = (const float*)d_in[2];
  const float* Tau_p   = (const float*)d_in[3];
  const float* Lambda_p = (const float*)d_in[4];
  const float* A_p     = (const float*)d_in[5];
  const float* b_p     = (const float*)d_in[6];

  float* out = (float*)d_out;
  float* z_out  = out;                                    // T*D
  float* kl_out = out + (size_t)T_DIM * D_DIM;            // 1
  float* Ex_out = kl_out + 1;                             // T*D
  float* Exx_out = Ex_out + (size_t)T_DIM * D_DIM;        // T*D
  float* kl_partials = (float*)d_ws;                      // NBLK floats

  pgm_lds_kernel<<<dim3(NBLK), dim3(BLK), 0, stream>>>(
      recog_J, recog_h, loc_p, Tau_p, Lambda_p, A_p, b_p,
      z_out, Ex_out, Exx_out, kl_partials);
  kl_reduce_kernel<<<dim3(1), dim3(BLK), 0, stream>>>(kl_partials, kl_out);
}

// Round 15
// 41.184 us; speedup vs baseline: 1.3118x; 1.3118x over previous
//
#include <hip/hip_runtime.h>
#include <stdint.h>

#define D_DIM 262144
#define T_DIM 24
#define S_DIM 12
#define BLK 256
#define NBLK (D_DIM / BLK)   // 1024 blocks
#define LDS_T 19             // timesteps staged in LDS (2*19*256*4 = 38.9 KB)

static constexpr float EPSF = 1e-6f;

// ---------------- threefry2x32, key = (0,0), 20 rounds ----------------
__device__ __forceinline__ void tf_round(unsigned& x0, unsigned& x1, int r) {
  x0 += x1;
  x1 = (x1 << r) | (x1 >> (32 - r));
  x1 ^= x0;
}

__device__ __forceinline__ void threefry00(unsigned c0, unsigned c1,
                                           unsigned& o0, unsigned& o1) {
  const unsigned ks0 = 0u, ks1 = 0u, ks2 = 0x1BD11BDAu;
  unsigned x0 = c0 + ks0, x1 = c1 + ks1;
  tf_round(x0, x1, 13); tf_round(x0, x1, 15); tf_round(x0, x1, 26); tf_round(x0, x1, 6);
  x0 += ks1; x1 += ks2 + 1u;
  tf_round(x0, x1, 17); tf_round(x0, x1, 29); tf_round(x0, x1, 16); tf_round(x0, x1, 24);
  x0 += ks2; x1 += ks0 + 2u;
  tf_round(x0, x1, 13); tf_round(x0, x1, 15); tf_round(x0, x1, 26); tf_round(x0, x1, 6);
  x0 += ks0; x1 += ks1 + 3u;
  tf_round(x0, x1, 17); tf_round(x0, x1, 29); tf_round(x0, x1, 16); tf_round(x0, x1, 24);
  x0 += ks1; x1 += ks2 + 4u;
  tf_round(x0, x1, 13); tf_round(x0, x1, 15); tf_round(x0, x1, 26); tf_round(x0, x1, 6);
  x0 += ks2; x1 += ks0 + 5u;
  o0 = x0; o1 = x1;
}

// bits -> uniform in [-0.99999994, 1) -> sqrt(2)*erfinv(u)  (XLA f32 path)
__device__ __forceinline__ float bits_to_normal(unsigned bits) {
  const float lo = -0.99999994f;
  const float hi = 1.0f;
  unsigned fb = (bits >> 9) | 0x3f800000u;
  float f = __uint_as_float(fb) - 1.0f;      // [0,1)
  float u = f * (hi - lo) + lo;
  u = fmaxf(lo, u);
  float w = -__logf(fmaf(-u, u, 1.0f));
  float p;
  if (w < 5.0f) {
    w = w - 2.5f;
    p = 2.81022636e-08f;
    p = fmaf(p, w, 3.43273939e-07f);
    p = fmaf(p, w, -3.5233877e-06f);
    p = fmaf(p, w, -4.39150654e-06f);
    p = fmaf(p, w, 0.00021858087f);
    p = fmaf(p, w, -0.00125372503f);
    p = fmaf(p, w, -0.00417768164f);
    p = fmaf(p, w, 0.246640727f);
    p = fmaf(p, w, 1.50140941f);
  } else {
    w = sqrtf(w) - 3.0f;
    p = -0.000200214257f;
    p = fmaf(p, w, 0.000100950558f);
    p = fmaf(p, w, 0.00134934322f);
    p = fmaf(p, w, -0.00367342844f);
    p = fmaf(p, w, 0.00573950773f);
    p = fmaf(p, w, -0.0076224613f);
    p = fmaf(p, w, 0.00943887047f);
    p = fmaf(p, w, 1.00167406f);
    p = fmaf(p, w, 2.83297682f);
  }
  return 1.41421356237309515f * (p * u);
}

// R12 verbatim — the measured optimum (42.0 us). Sweet spot: VGPR=108
// (<=128 -> 4 waves/SIMD), LDS 39.4 KB (4 blocks/CU), grid 4 blocks/CU.
// R13 (no LDS: VGPR 136) and R14 (reconstruction: VGPR 152) both crossed
// the 128-VGPR cliff and lost ~12 us. NT stores keep outputs out of the
// caches (R12: -4.7 us). Natural VGPR — no launch_bounds min-arg (R2/R9).
__global__ __launch_bounds__(256) void pgm_lds_kernel(
    const float* __restrict__ recog_J, const float* __restrict__ recog_h,
    const float* __restrict__ loc_p, const float* __restrict__ Tau_p,
    const float* __restrict__ Lambda_p, const float* __restrict__ A_p,
    const float* __restrict__ b_p,
    float* __restrict__ z_out,
    float* __restrict__ Ex_out, float* __restrict__ Exx_out,
    float* __restrict__ kl_partials) {
  __shared__ float s_rJ[LDS_T * BLK];
  __shared__ float s_rh[LDS_T * BLK];
  __shared__ float s_kl[BLK / 64];
  const int tid = threadIdx.x;
  const int d = blockIdx.x * BLK + tid;

#define RJ(t) (((t) < LDS_T) ? s_rJ[(t) * BLK + tid]                           \
                             : recog_J[(size_t)(t) * D_DIM + d])
#define RH(t) (((t) < LDS_T) ? s_rh[(t) * BLK + tid]                           \
                             : recog_h[(size_t)(t) * D_DIM + d])

  // ---- bulk stage: 38 direct global->LDS loads, no VGPR round-trip ----
#pragma unroll
  for (int t = 0; t < LDS_T; ++t) {
    __builtin_amdgcn_global_load_lds(
        (const __attribute__((address_space(1))) uint32_t*)(uintptr_t)(recog_J + (size_t)t * D_DIM + d),
        (__attribute__((address_space(3))) uint32_t*)(uintptr_t)(s_rJ + t * BLK + tid),
        4, 0, 0);
    __builtin_amdgcn_global_load_lds(
        (const __attribute__((address_space(1))) uint32_t*)(uintptr_t)(recog_h + (size_t)t * D_DIM + d),
        (__attribute__((address_space(3))) uint32_t*)(uintptr_t)(s_rh + t * BLK + tid),
        4, 0, 0);
  }

  // ---- params into registers; p_logZ terms (log-product form) ----
  float lam[S_DIM], Aa[S_DIM], hb[S_DIM];
  float kld = 0.0f;
  float prodA = 1.0f;   // prod_{s<11} lam_s  (sum log -> log prod)
#pragma unroll
  for (int s = 0; s < S_DIM; ++s) {
    float L = Lambda_p[s * D_DIM + d];
    float a = A_p[s * D_DIM + d];
    float bb = b_p[s * D_DIM + d];
    float l = L * L + EPSF;
    lam[s] = l;
    Aa[s] = a;
    hb[s] = l * bb;
    float wgt = (s < 11) ? 1.0f : 0.5f;   // _tile: s=0..10 twice, s=11 once
    kld += wgt * (hb[s] * bb);
    if (s < 11) prodA *= l;
  }
  float tau, tau_mu;
  {
    float Tv = Tau_p[d];
    float lv = loc_p[d];
    tau = Tv * Tv + EPSF;
    tau_mu = tau * lv;
    kld += 0.5f * (tau * lv * lv);
  }
  kld -= __logf(prodA) + 0.5f * __logf(lam[11] * tau);

  __syncthreads();   // drains vmcnt(0): staging + param loads complete

  // ---- forward information filter ----
  float fJ[T_DIM], fh[T_DIM];
  fJ[0] = tau + RJ(0);
  fh[0] = tau_mu + RH(0);
  float prodD = 1.0f;   // prod of denoms, split at t=11 to bound magnitude
#pragma unroll
  for (int t = 0; t < T_DIM - 1; ++t) {
    const int s = (t < 12) ? t : t - 12;
    float l = lam[s], a = Aa[s];
    float jab = a * l;
    float jaa = a * jab;
    float ha = -a * hb[s];
    float denom = fJ[t] + jaa;
    float inv = __builtin_amdgcn_rcpf(denom);
    float hc = fh[t] + ha;
    prodD *= denom;
    kld += -0.5f * hc * hc * inv;          // -= q_logZ step (log via product)
    if (t == 11) { kld += 0.5f * __logf(prodD); prodD = 1.0f; }
    fJ[t + 1] = l - jab * jab * inv + RJ(t + 1);
    fh[t + 1] = hb[s] + jab * hc * inv + RH(t + 1);
  }
  const float fJT = fJ[T_DIM - 1];
  const float fhT = fh[T_DIM - 1];
  const float invT = __builtin_amdgcn_rcpf(fJT);
  prodD *= fJT;
  kld += 0.5f * __logf(prodD) - 0.5f * fhT * fhT * invT;   // -= q_logZ final

  // ---- t = 23 ----
  float eps_st[S_DIM];   // stash eps[0..11] while consuming eps[12..23]
  float ExT = fhT * invT;
  float VarT = invT;
  float eps23;
  {
    unsigned o0, o1;
    threefry00((unsigned)(11 * D_DIM + d), (unsigned)(23 * D_DIM + d), o0, o1);
    eps_st[11] = bits_to_normal(o0);
    eps23 = bits_to_normal(o1);
  }
  float zT = ExT + eps23 * sqrtf(invT);
  float ExxT = VarT + ExT * ExT;
  kld += -0.5f * RJ(T_DIM - 1) * ExxT + RH(T_DIM - 1) * ExT;
  __builtin_nontemporal_store(zT, &z_out[(T_DIM - 1) * D_DIM + d]);
  __builtin_nontemporal_store(ExT, &Ex_out[(T_DIM - 1) * D_DIM + d]);
  __builtin_nontemporal_store(ExxT, &Exx_out[(T_DIM - 1) * D_DIM + d]);

  // ---- fused backward: RTS smoother + posterior sample + KL stats ----
  float Exn = ExT, Varn = VarT, zn = zT;
#pragma unroll
  for (int t = T_DIM - 2; t >= 0; --t) {
    const int s = (t < 12) ? t : t - 12;
    float l = lam[s], a = Aa[s];
    float jab = a * l;
    float jaa = a * jab;
    float ha = -a * hb[s];
    float denom = fJ[t] + jaa;
    float inv = __builtin_amdgcn_rcpf(denom);
    float hc = fh[t] + ha;

    float e;
    if (t >= 12) {
      unsigned o0, o1;
      threefry00((unsigned)((t - 12) * D_DIM + d), (unsigned)(t * D_DIM + d), o0, o1);
      eps_st[t - 12] = bits_to_normal(o0);
      e = bits_to_normal(o1);
    } else {
      e = eps_st[t];
    }

    float g = jab * inv;
    float Ex = (hc + jab * Exn) * inv;
    float Var = inv + g * g * Varn;
    float zt = (hc + jab * zn) * inv + e * sqrtf(inv);
    float Exx = Var + Ex * Ex;
    kld += -0.5f * RJ(t) * Exx + RH(t) * Ex;

    __builtin_nontemporal_store(zt, &z_out[t * D_DIM + d]);
    __builtin_nontemporal_store(Ex, &Ex_out[t * D_DIM + d]);
    __builtin_nontemporal_store(Exx, &Exx_out[t * D_DIM + d]);

    Exn = Ex; Varn = Var; zn = zt;
  }

  // ---- KL reduction: wave shuffle -> LDS -> one plain store per block ----
#pragma unroll
  for (int off = 32; off > 0; off >>= 1)
    kld += __shfl_down(kld, off, 64);
  if ((tid & 63) == 0)
    s_kl[tid >> 6] = kld;
  __syncthreads();
  if (tid == 0)
    kl_partials[blockIdx.x] = s_kl[0] + s_kl[1] + s_kl[2] + s_kl[3];
}

// Finisher: one block sums the 1024 per-block partials -> kl_out.
__global__ __launch_bounds__(256) void kl_reduce_kernel(
    const float* __restrict__ kl_partials, float* __restrict__ kl_out) {
  __shared__ float s_kl[BLK / 64];
  float v = 0.0f;
#pragma unroll
  for (int i = 0; i < NBLK / BLK; ++i)
    v += kl_partials[i * BLK + threadIdx.x];
#pragma unroll
  for (int off = 32; off > 0; off >>= 1)
    v += __shfl_down(v, off, 64);
  if ((threadIdx.x & 63) == 0)
    s_kl[threadIdx.x >> 6] = v;
  __syncthreads();
  if (threadIdx.x == 0)
    kl_out[0] = s_kl[0] + s_kl[1] + s_kl[2] + s_kl[3];
}

extern "C" void kernel_launch(void* const* d_in, const int* in_sizes, int n_in,
                              void* d_out, int out_size, void* d_ws, size_t ws_size,
                              hipStream_t stream) {
  const float* recog_J = (const float*)d_in[0];
  const float* recog_h = (const float*)d_in[1];
  const float* loc_p   = (const float*)d_in[2];
  const float* Tau_p   = (const float*)d_in[3];
  const float* Lambda_p = (const float*)d_in[4];
  const float* A_p     = (const float*)d_in[5];
  const float* b_p     = (const float*)d_in[6];

  float* out = (float*)d_out;
  float* z_out  = out;                                    // T*D
  float* kl_out = out + (size_t)T_DIM * D_DIM;            // 1
  float* Ex_out = kl_out + 1;                             // T*D
  float* Exx_out = Ex_out + (size_t)T_DIM * D_DIM;        // T*D
  float* kl_partials = (float*)d_ws;                      // NBLK floats

  pgm_lds_kernel<<<dim3(NBLK), dim3(BLK), 0, stream>>>(
      recog_J, recog_h, loc_p, Tau_p, Lambda_p, A_p, b_p,
      z_out, Ex_out, Exx_out, kl_partials);
  kl_reduce_kernel<<<dim3(1), dim3(BLK), 0, stream>>>(kl_partials, kl_out);
}